// Round 3
// baseline (552.052 us; speedup 1.0000x reference)
//
#include <hip/hip_runtime.h>

// Swin-3D window attention fwd. B_=256, nW=128, N1=N2=256, C=256, H=8, hd=32.
#define BH_TOTAL 2048
#define SCALE_Q 0.17677669529663687f

typedef unsigned short ushort;
typedef unsigned int uint;
typedef __attribute__((ext_vector_type(8))) short bf16x8;   // 8 bf16 = 4 VGPRs
typedef __attribute__((ext_vector_type(4))) ushort u16x4;
typedef __attribute__((ext_vector_type(4))) float f32x4;

static __device__ __forceinline__ ushort f2bf(float f) {      // RNE
    union { float f; uint u; } v; v.f = f;
    uint r = (v.u + 0x7fffu + ((v.u >> 16) & 1u)) >> 16;
    return (ushort)r;
}
static __device__ __forceinline__ ushort bfru(float f) {      // round-half-up (hot path)
    union { float f; uint u; } v; v.f = f;
    return (ushort)((v.u + 0x8000u) >> 16);
}
static __device__ __forceinline__ float bflo(uint w) {
    union { uint u; float f; } v; v.u = w << 16; return v.f;
}
static __device__ __forceinline__ float bfhi(uint w) {
    union { uint u; float f; } v; v.u = w & 0xffff0000u; return v.f;
}

// ---------------------------------------------------------------------------
// One-shot fp32 -> bf16 conversion of q, kv, Wq, Wkv, Wp.
// ---------------------------------------------------------------------------
__global__ __launch_bounds__(256)
void cvt_all(const float* __restrict__ q, const float* __restrict__ kv,
             const float* __restrict__ Wq, const float* __restrict__ Wkv,
             const float* __restrict__ Wp,
             ushort* __restrict__ qb, ushort* __restrict__ kvb,
             ushort* __restrict__ wqb, ushort* __restrict__ wkvb,
             ushort* __restrict__ wpb)
{
    const int bid = blockIdx.x, tid = threadIdx.x;
    const float* src; ushort* dst; int base;
    if (bid < 8192)       { src = q;   dst = qb;   base = bid; }
    else if (bid < 16384) { src = kv;  dst = kvb;  base = bid - 8192; }
    else if (bid < 16416) { src = Wq;  dst = wqb;  base = bid - 16384; }
    else if (bid < 16480) { src = Wkv; dst = wkvb; base = bid - 16416; }
    else                  { src = Wp;  dst = wpb;  base = bid - 16480; }
    size_t off = ((size_t)base * 256 + tid) * 8;
    float4 a = *(const float4*)&src[off];
    float4 b = *(const float4*)&src[off + 4];
    bf16x8 p = {(short)f2bf(a.x), (short)f2bf(a.y), (short)f2bf(a.z), (short)f2bf(a.w),
                (short)f2bf(b.x), (short)f2bf(b.y), (short)f2bf(b.z), (short)f2bf(b.w)};
    *(bf16x8*)&dst[off] = p;
}

// ---------------------------------------------------------------------------
// Swapped-QK lane layout: lane (col,quad) reg (jt,r) holds value at
// [q=col][j = jt*16 + quad*4 + r].  Flat per-lane index i = quad*64+jt*4+r.
// maskP[w][q][i] = mask[w][q][j(i)],  j(i) = ((i>>2)&15)*16 + (i>>6)*4 + (i&3)
// grid: (w, qb) = 128*64 blocks, 4 q-rows per block.
// ---------------------------------------------------------------------------
__global__ __launch_bounds__(256)
void mask_pre(const float* __restrict__ mask, ushort* __restrict__ maskP)
{
    __shared__ float rows[1024];
    const int w = blockIdx.x >> 6, qb = blockIdx.x & 63;
    const int tid = threadIdx.x;
    const float* src = mask + (size_t)w * 65536 + qb * 1024;
    #pragma unroll
    for (int i = 0; i < 4; ++i) rows[tid + 256 * i] = src[tid + 256 * i];
    __syncthreads();
    const int row = tid >> 6;          // 0..3
    const int ib  = (tid & 63) * 4;    // i base (4-aligned: r = i&3)
    u16x4 p;
    #pragma unroll
    for (int r = 0; r < 4; ++r) {
        int i = ib + r;
        int j = ((i >> 2) & 15) * 16 + (i >> 6) * 4 + (i & 3);
        p[r] = f2bf(rows[row * 256 + j]);
    }
    *(u16x4*)&maskP[(size_t)w * 65536 + (qb * 4 + row) * 256 + ib] = p;
}

// biasP[h][q][i] = bias_table[rel_index[q*256 + j(i)]*8 + h]  (bf16)
// grid: (h, qb) = 8*64 blocks
__global__ __launch_bounds__(256)
void bias_pre(const float* __restrict__ bias_table, const int* __restrict__ rel_index,
              ushort* __restrict__ biasP)
{
    __shared__ int idx[1024];
    const int h = blockIdx.x >> 6, qb = blockIdx.x & 63;
    const int tid = threadIdx.x;
    const int* src = rel_index + qb * 1024;
    #pragma unroll
    for (int i = 0; i < 4; ++i) idx[tid + 256 * i] = src[tid + 256 * i];
    __syncthreads();
    const int row = tid >> 6;
    const int ib  = (tid & 63) * 4;
    u16x4 p;
    #pragma unroll
    for (int r = 0; r < 4; ++r) {
        int i = ib + r;
        int j = ((i >> 2) & 15) * 16 + (i >> 6) * 4 + (i & 3);
        p[r] = f2bf(bias_table[idx[row * 256 + j] * 8 + h]);
    }
    *(u16x4*)&biasP[(size_t)h * 65536 + (qb * 4 + row) * 256 + ib] = p;
}

// ---------------------------------------------------------------------------
// bf16-MFMA GEMM: C(M x N) = A(M x 256) @ W(N x 256)^T + bias.
// Pre-converted bf16 A/W -> staging is pure b128 copies.
// MODE 1 V-half stores with k-permutation sigma (j' digit layout kc|quad|t2|r)
// so attn's PV can consume P directly from registers.
// ---------------------------------------------------------------------------
template<int MODE>
__global__ __launch_bounds__(256)
void gemm_mfma(const ushort* __restrict__ A, const ushort* __restrict__ W,
               const float* __restrict__ bias, float* __restrict__ outf,
               ushort* __restrict__ outh0, ushort* __restrict__ outh1)
{
    __shared__ ushort As[128 * 72];   // [m][k], stride 64+8
    __shared__ ushort Bs[128 * 72];   // [n][k]

    const int tid  = threadIdx.x;
    const int n0   = blockIdx.x * 128;
    const int m0   = blockIdx.y * 128;
    const int lane = tid & 63, wave = tid >> 6;
    const int col  = lane & 15, quad = lane >> 4;
    const int wm   = (wave >> 1) * 64, wn = (wave & 1) * 64;

    f32x4 acc[4][4];
    #pragma unroll
    for (int i = 0; i < 4; ++i)
        #pragma unroll
        for (int j = 0; j < 4; ++j)
            acc[i][j] = (f32x4){0.f, 0.f, 0.f, 0.f};

    for (int k0 = 0; k0 < 256; k0 += 64) {
        __syncthreads();
        #pragma unroll
        for (int i = 0; i < 4; ++i) {
            int f = tid + 256 * i;            // 1024 bf16x8 chunks
            int row = f >> 3, c8 = f & 7;
            *(bf16x8*)&As[row * 72 + c8 * 8] =
                *(const bf16x8*)&A[(size_t)(m0 + row) * 256 + k0 + c8 * 8];
        }
        #pragma unroll
        for (int i = 0; i < 4; ++i) {
            int f = tid + 256 * i;
            int row = f >> 3, c8 = f & 7;
            *(bf16x8*)&Bs[row * 72 + c8 * 8] =
                *(const bf16x8*)&W[(size_t)(n0 + row) * 256 + k0 + c8 * 8];
        }
        __syncthreads();
        #pragma unroll
        for (int ks = 0; ks < 64; ks += 32) {
            bf16x8 af[4], bfr[4];
            #pragma unroll
            for (int t = 0; t < 4; ++t) {
                af[t]  = *(const bf16x8*)&As[(wm + t * 16 + col) * 72 + ks + quad * 8];
                bfr[t] = *(const bf16x8*)&Bs[(wn + t * 16 + col) * 72 + ks + quad * 8];
            }
            #pragma unroll
            for (int mt = 0; mt < 4; ++mt)
                #pragma unroll
                for (int nt = 0; nt < 4; ++nt)
                    acc[mt][nt] = __builtin_amdgcn_mfma_f32_16x16x32_bf16(
                        af[mt], bfr[nt], acc[mt][nt], 0, 0, 0);
        }
    }

    // epilogue: m = m0+wm+mt*16+quad*4+r, n = n0+wn+nt*16+col
    #pragma unroll
    for (int mt = 0; mt < 4; ++mt) {
        const int mb = m0 + wm + mt * 16 + quad * 4;
        #pragma unroll
        for (int nt = 0; nt < 4; ++nt) {
            const int n = n0 + wn + nt * 16 + col;
            const float bn = bias[n];
            if (MODE == 1 && n >= 256) {
                // V: transposed, with sigma applied to token index (r in bits
                // 1:0 survives -> u16x4 store stays vectorized)
                const int nn = n - 256;
                const int b = mb >> 8, m1 = mb & 255;
                const int m1p = (m1 & 0xE3) | ((m1 & 0x0C) << 1) | ((m1 & 0x10) >> 2);
                u16x4 p;
                #pragma unroll
                for (int r = 0; r < 4; ++r)
                    p[r] = f2bf(acc[mt][nt][r] + bn);
                *(u16x4*)&outh1[(size_t)((b << 3) | (nn >> 5)) * 8192
                                + (nn & 31) * 256 + m1p] = p;
            } else {
                #pragma unroll
                for (int r = 0; r < 4; ++r) {
                    int m = mb + r;
                    int b = m >> 8, m1 = m & 255;
                    float v = acc[mt][nt][r] + bn;
                    if (MODE == 0) {
                        outh0[(size_t)((b << 3) | (n >> 5)) * 8192 + m1 * 32 + (n & 31)]
                            = f2bf(v * SCALE_Q);
                    } else if (MODE == 1) {
                        outh0[(size_t)((b << 3) | (n >> 5)) * 8192 + m1 * 32 + (n & 31)]
                            = f2bf(v);
                    } else {
                        outf[(size_t)m * 256 + n] = v;
                    }
                }
            }
        }
    }
}

// ---------------------------------------------------------------------------
// MFMA attention, swapped-operand QK^T (S^T = K @ Q^T): lane (col,quad) holds
// S[q=q0+col][j=jt*16+quad*4+r].  Softmax is lane-local + 2 shfl_xor.
// PV A-fragment packed directly from registers (k-dim permuted by sigma,
// matching vtb's layout) -> NO P LDS round-trip.  LDS 37376B -> 4 blocks/CU.
// ---------------------------------------------------------------------------
__global__ __launch_bounds__(256, 4)
void attn_mfma(const ushort* __restrict__ qh, const ushort* __restrict__ kb,
               const ushort* __restrict__ vt, const ushort* __restrict__ maskP,
               const ushort* __restrict__ biasP, ushort* __restrict__ xbuf)
{
    __shared__ ushort Ks[256 * 40];    // [j][d], stride 32+8
    __shared__ ushort Vts[32 * 264];   // [d][j'], stride 256+8

    // swizzle: g = w*16 + (b2*8 + h); window-sharing blocks adjacent
    const int g  = blockIdx.x;
    const int w  = g >> 4;
    const int b2 = (g >> 3) & 1, h = g & 7;
    const int b  = b2 * 128 + w;
    const int bh = b * 8 + h;

    const int tid  = threadIdx.x;
    const int lane = tid & 63, wave = tid >> 6;
    const int col  = lane & 15;
    const int quad = lane >> 4;

    const ushort* __restrict__ Qg = qh + (size_t)bh * 8192;
    const ushort* __restrict__ Kg = kb + (size_t)bh * 8192;
    const ushort* __restrict__ Vg = vt + (size_t)bh * 8192;
    const ushort* __restrict__ Mg = maskP + (size_t)w * 65536;
    const ushort* __restrict__ Bg = biasP + (size_t)h * 65536;

    for (int t = tid; t < 1024; t += 256) {
        int j = t >> 2, p = t & 3;
        *(bf16x8*)&Ks[j * 40 + p * 8] = *(const bf16x8*)&Kg[j * 32 + p * 8];
    }
    for (int t = tid; t < 1024; t += 256) {
        int d = t >> 5, p = t & 31;
        *(bf16x8*)&Vts[d * 264 + p * 8] = *(const bf16x8*)&Vg[d * 256 + p * 8];
    }
    __syncthreads();

    const f32x4 zero = {0.f, 0.f, 0.f, 0.f};

    for (int it = 0; it < 4; ++it) {
        const int q0   = (wave * 4 + it) * 16;
        const int qrow = q0 + col;

        // per-(q,quad) slice: 64 ushorts, local index l = jt*4 + r
        const ushort* mp  = &Mg[(size_t)qrow * 256 + quad * 64];
        const ushort* bp2 = &Bg[(size_t)qrow * 256 + quad * 64];

        // B operand: Q fragment (this wave's 16 q-rows)
        bf16x8 fq = *(const bf16x8*)&Qg[(size_t)qrow * 32 + quad * 8];

        // QK^T swapped: acc[jt][r] = S[q=qrow][j=jt*16+quad*4+r]
        f32x4 acc[16];
        #pragma unroll
        for (int jt = 0; jt < 16; ++jt) {
            bf16x8 fk = *(const bf16x8*)&Ks[(jt * 16 + col) * 40 + quad * 8];
            acc[jt] = __builtin_amdgcn_mfma_f32_16x16x32_bf16(fk, fq, zero, 0, 0, 0);
        }

        // mask + bias post-add (bf16 pairs), two halves to limit VGPR peak.
        // uint4 i covers l = half*32 + i*8 .. +8  (8 ushorts = 2 jt's).
        #pragma unroll
        for (int half = 0; half < 2; ++half) {
            uint4 mw[4], bw[4];
            #pragma unroll
            for (int i = 0; i < 4; ++i) {
                mw[i] = *(const uint4*)(mp  + half * 32 + i * 8);
                bw[i] = *(const uint4*)(bp2 + half * 32 + i * 8);
            }
            #pragma unroll
            for (int jt8 = 0; jt8 < 8; ++jt8) {
                const int jt = half * 8 + jt8;
                uint4 mv4 = mw[jt8 >> 1];
                uint4 bv4 = bw[jt8 >> 1];
                uint mu0 = (jt8 & 1) ? mv4.z : mv4.x;
                uint mu1 = (jt8 & 1) ? mv4.w : mv4.y;
                uint bu0 = (jt8 & 1) ? bv4.z : bv4.x;
                uint bu1 = (jt8 & 1) ? bv4.w : bv4.y;
                acc[jt][0] += bflo(mu0) + bflo(bu0);
                acc[jt][1] += bfhi(mu0) + bfhi(bu0);
                acc[jt][2] += bflo(mu1) + bflo(bu1);
                acc[jt][3] += bfhi(mu1) + bfhi(bu1);
            }
        }

        // softmax over j for q=qrow: lane-local tree + cross-quad shfl
        float mv[16];
        #pragma unroll
        for (int jt = 0; jt < 16; ++jt)
            mv[jt] = fmaxf(fmaxf(acc[jt][0], acc[jt][1]),
                           fmaxf(acc[jt][2], acc[jt][3]));
        #pragma unroll
        for (int st = 8; st >= 1; st >>= 1)
            #pragma unroll
            for (int i = 0; i < 8; ++i)
                if (i < st) mv[i] = fmaxf(mv[i], mv[i + st]);
        float m = mv[0];
        m = fmaxf(m, __shfl_xor(m, 16));
        m = fmaxf(m, __shfl_xor(m, 32));

        float sv[16];
        #pragma unroll
        for (int jt = 0; jt < 16; ++jt) {
            #pragma unroll
            for (int r = 0; r < 4; ++r) {
                float e = __expf(acc[jt][r] - m);
                acc[jt][r] = e;
            }
            sv[jt] = (acc[jt][0] + acc[jt][1]) + (acc[jt][2] + acc[jt][3]);
        }
        #pragma unroll
        for (int st = 8; st >= 1; st >>= 1)
            #pragma unroll
            for (int i = 0; i < 8; ++i)
                if (i < st) sv[i] += sv[i + st];
        float s = sv[0];
        s += __shfl_xor(s, 16);
        s += __shfl_xor(s, 32);
        const float inv = 1.0f / s;

        // pack P (prescaled) straight from registers: k-slot (quad,t) of PV
        // call kc holds j = (2kc + t>>2)*16 + quad*4 + (t&3)  == sigma layout
        bf16x8 pa[8];
        #pragma unroll
        for (int kc = 0; kc < 8; ++kc)
            #pragma unroll
            for (int t2 = 0; t2 < 2; ++t2)
                #pragma unroll
                for (int r = 0; r < 4; ++r)
                    pa[kc][t2 * 4 + r] = (short)bfru(acc[kc * 2 + t2][r] * inv);

        // PV: x[q][d] accumulated over permuted j'
        f32x4 x0 = zero, x1 = zero;
        #pragma unroll
        for (int kc = 0; kc < 8; ++kc) {
            bf16x8 bv0 = *(const bf16x8*)&Vts[col * 264 + kc * 32 + quad * 8];
            bf16x8 bv1 = *(const bf16x8*)&Vts[(col + 16) * 264 + kc * 32 + quad * 8];
            x0 = __builtin_amdgcn_mfma_f32_16x16x32_bf16(pa[kc], bv0, x0, 0, 0, 0);
            x1 = __builtin_amdgcn_mfma_f32_16x16x32_bf16(pa[kc], bv1, x1, 0, 0, 0);
        }

        // out: lane holds O[q0+quad*4+r][d=col(+16)]
        #pragma unroll
        for (int r = 0; r < 4; ++r) {
            int row = q0 + quad * 4 + r;
            size_t base = (size_t)(b * 256 + row) * 256 + h * 32;
            xbuf[base + col]      = f2bf(x0[r]);
            xbuf[base + 16 + col] = f2bf(x1[r]);
        }
    }
}

// ---------------------------------------------------------------------------
extern "C" void kernel_launch(void* const* d_in, const int* in_sizes, int n_in,
                              void* d_out, int out_size, void* d_ws, size_t ws_size,
                              hipStream_t stream)
{
    const float* q          = (const float*)d_in[0];
    const float* kv         = (const float*)d_in[1];
    const float* mask       = (const float*)d_in[2];
    const float* Wq         = (const float*)d_in[3];
    const float* bq         = (const float*)d_in[4];
    const float* Wkv        = (const float*)d_in[5];
    const float* bkv        = (const float*)d_in[6];
    const float* bias_table = (const float*)d_in[7];
    const float* Wp         = (const float*)d_in[8];
    const float* bp         = (const float*)d_in[9];
    const int*   rel_index  = (const int*)d_in[10];
    float* out = (float*)d_out;

    // ws layout (with phase aliasing):
    //   0      qhb   32MB
    //  32M     qb16 (phase1) -> kbb (phase2)   32MB
    //  64M     vtb   32MB
    //  96M     kvb16 (phase1) -> xb (phase2)   32MB
    // 128M     maskP bf16 16MB
    // 144M     biasP bf16 1MB (2MB slot)
    // 146M     Wq/Wkv/Wp bf16
    char* ws = (char*)d_ws;
    ushort* qhb   = (ushort*)(ws);
    ushort* qb16  = (ushort*)(ws + (size_t)33554432);
    ushort* kbb   = (ushort*)(ws + (size_t)33554432);
    ushort* vtb   = (ushort*)(ws + (size_t)67108864);
    ushort* kvb16 = (ushort*)(ws + (size_t)100663296);
    ushort* xb    = (ushort*)(ws + (size_t)100663296);
    ushort* mP    = (ushort*)(ws + (size_t)134217728);
    ushort* bP    = (ushort*)(ws + (size_t)150994944);
    ushort* wqb   = (ushort*)(ws + (size_t)153092096);
    ushort* wkvb  = (ushort*)(ws + (size_t)153223168);
    ushort* wpb   = (ushort*)(ws + (size_t)153485312);

    dim3 blk(256);
    cvt_all<<<dim3(16512), blk, 0, stream>>>(q, kv, Wq, Wkv, Wp,
                                             qb16, kvb16, wqb, wkvb, wpb);
    mask_pre<<<dim3(8192), blk, 0, stream>>>(mask, mP);
    bias_pre<<<dim3(512),  blk, 0, stream>>>(bias_table, rel_index, bP);
    gemm_mfma<0><<<dim3(2, 512), blk, 0, stream>>>(qb16,  wqb,  bq,  nullptr, qhb, nullptr);
    gemm_mfma<1><<<dim3(4, 512), blk, 0, stream>>>(kvb16, wkvb, bkv, nullptr, kbb, vtb);
    attn_mfma<<<dim3(BH_TOTAL), blk, 0, stream>>>(qhb, kbb, vtb, mP, bP, xb);
    gemm_mfma<2><<<dim3(2, 512), blk, 0, stream>>>(xb, wpb, bp, out, nullptr, nullptr);
}

// Round 4
// 442.218 us; speedup vs baseline: 1.2484x; 1.2484x over previous
//
#include <hip/hip_runtime.h>

// Swin-3D window attention fwd. B_=256, nW=128, N1=N2=256, C=256, H=8, hd=32.
#define BH_TOTAL 2048
#define SCALE_Q 0.17677669529663687f

typedef unsigned short ushort;
typedef unsigned int uint;
typedef __attribute__((ext_vector_type(8))) short bf16x8;   // 8 bf16 = 4 VGPRs
typedef __attribute__((ext_vector_type(4))) ushort u16x4;
typedef __attribute__((ext_vector_type(4))) float f32x4;

static __device__ __forceinline__ ushort f2bf(float f) {      // RNE
    union { float f; uint u; } v; v.f = f;
    uint r = (v.u + 0x7fffu + ((v.u >> 16) & 1u)) >> 16;
    return (ushort)r;
}
static __device__ __forceinline__ ushort bfru(float f) {      // round-half-up (hot path)
    union { float f; uint u; } v; v.f = f;
    return (ushort)((v.u + 0x8000u) >> 16);
}
static __device__ __forceinline__ float bflo(uint w) {
    union { uint u; float f; } v; v.u = w << 16; return v.f;
}
static __device__ __forceinline__ float bfhi(uint w) {
    union { uint u; float f; } v; v.u = w & 0xffff0000u; return v.f;
}

// ---------------------------------------------------------------------------
// One-shot fp32 -> bf16 conversion of q, kv, Wq, Wkv, Wp.
// ---------------------------------------------------------------------------
__global__ __launch_bounds__(256)
void cvt_all(const float* __restrict__ q, const float* __restrict__ kv,
             const float* __restrict__ Wq, const float* __restrict__ Wkv,
             const float* __restrict__ Wp,
             ushort* __restrict__ qb, ushort* __restrict__ kvb,
             ushort* __restrict__ wqb, ushort* __restrict__ wkvb,
             ushort* __restrict__ wpb)
{
    const int bid = blockIdx.x, tid = threadIdx.x;
    const float* src; ushort* dst; int base;
    if (bid < 8192)       { src = q;   dst = qb;   base = bid; }
    else if (bid < 16384) { src = kv;  dst = kvb;  base = bid - 8192; }
    else if (bid < 16416) { src = Wq;  dst = wqb;  base = bid - 16384; }
    else if (bid < 16480) { src = Wkv; dst = wkvb; base = bid - 16416; }
    else                  { src = Wp;  dst = wpb;  base = bid - 16480; }
    size_t off = ((size_t)base * 256 + tid) * 8;
    float4 a = *(const float4*)&src[off];
    float4 b = *(const float4*)&src[off + 4];
    bf16x8 p = {(short)f2bf(a.x), (short)f2bf(a.y), (short)f2bf(a.z), (short)f2bf(a.w),
                (short)f2bf(b.x), (short)f2bf(b.y), (short)f2bf(b.z), (short)f2bf(b.w)};
    *(bf16x8*)&dst[off] = p;
}

// ---------------------------------------------------------------------------
// Swapped-QK lane layout: lane (col,quad) reg (jt,r) holds value at
// [q=col][j = jt*16 + quad*4 + r].  Flat per-lane index i = quad*64+jt*4+r.
// maskP[w][q][i] = mask[w][q][j(i)],  j(i) = ((i>>2)&15)*16 + (i>>6)*4 + (i&3)
// grid: (w, qb) = 128*64 blocks, 4 q-rows per block.
// ---------------------------------------------------------------------------
__global__ __launch_bounds__(256)
void mask_pre(const float* __restrict__ mask, ushort* __restrict__ maskP)
{
    __shared__ float rows[1024];
    const int w = blockIdx.x >> 6, qb = blockIdx.x & 63;
    const int tid = threadIdx.x;
    const float* src = mask + (size_t)w * 65536 + qb * 1024;
    #pragma unroll
    for (int i = 0; i < 4; ++i) rows[tid + 256 * i] = src[tid + 256 * i];
    __syncthreads();
    const int row = tid >> 6;          // 0..3
    const int ib  = (tid & 63) * 4;    // i base (4-aligned: r = i&3)
    u16x4 p;
    #pragma unroll
    for (int r = 0; r < 4; ++r) {
        int i = ib + r;
        int j = ((i >> 2) & 15) * 16 + (i >> 6) * 4 + (i & 3);
        p[r] = f2bf(rows[row * 256 + j]);
    }
    *(u16x4*)&maskP[(size_t)w * 65536 + (qb * 4 + row) * 256 + ib] = p;
}

// biasP[h][q][i] = bias_table[rel_index[q*256 + j(i)]*8 + h]  (bf16)
// grid: (h, qb) = 8*64 blocks
__global__ __launch_bounds__(256)
void bias_pre(const float* __restrict__ bias_table, const int* __restrict__ rel_index,
              ushort* __restrict__ biasP)
{
    __shared__ int idx[1024];
    const int h = blockIdx.x >> 6, qb = blockIdx.x & 63;
    const int tid = threadIdx.x;
    const int* src = rel_index + qb * 1024;
    #pragma unroll
    for (int i = 0; i < 4; ++i) idx[tid + 256 * i] = src[tid + 256 * i];
    __syncthreads();
    const int row = tid >> 6;
    const int ib  = (tid & 63) * 4;
    u16x4 p;
    #pragma unroll
    for (int r = 0; r < 4; ++r) {
        int i = ib + r;
        int j = ((i >> 2) & 15) * 16 + (i >> 6) * 4 + (i & 3);
        p[r] = f2bf(bias_table[idx[row * 256 + j] * 8 + h]);
    }
    *(u16x4*)&biasP[(size_t)h * 65536 + (qb * 4 + row) * 256 + ib] = p;
}

// ---------------------------------------------------------------------------
// bf16-MFMA GEMM: C(M x N) = A(M x 256) @ W(N x 256)^T + bias.
// Pre-converted bf16 A/W -> staging is pure b128 copies.
// MODE 1 V-half stores with k-permutation sigma (j' digit layout kc|quad|t2|r)
// so attn's PV can consume P directly from registers.
// ---------------------------------------------------------------------------
template<int MODE>
__global__ __launch_bounds__(256)
void gemm_mfma(const ushort* __restrict__ A, const ushort* __restrict__ W,
               const float* __restrict__ bias, float* __restrict__ outf,
               ushort* __restrict__ outh0, ushort* __restrict__ outh1)
{
    __shared__ ushort As[128 * 72];   // [m][k], stride 64+8
    __shared__ ushort Bs[128 * 72];   // [n][k]

    const int tid  = threadIdx.x;
    const int n0   = blockIdx.x * 128;
    const int m0   = blockIdx.y * 128;
    const int lane = tid & 63, wave = tid >> 6;
    const int col  = lane & 15, quad = lane >> 4;
    const int wm   = (wave >> 1) * 64, wn = (wave & 1) * 64;

    f32x4 acc[4][4];
    #pragma unroll
    for (int i = 0; i < 4; ++i)
        #pragma unroll
        for (int j = 0; j < 4; ++j)
            acc[i][j] = (f32x4){0.f, 0.f, 0.f, 0.f};

    for (int k0 = 0; k0 < 256; k0 += 64) {
        __syncthreads();
        #pragma unroll
        for (int i = 0; i < 4; ++i) {
            int f = tid + 256 * i;            // 1024 bf16x8 chunks
            int row = f >> 3, c8 = f & 7;
            *(bf16x8*)&As[row * 72 + c8 * 8] =
                *(const bf16x8*)&A[(size_t)(m0 + row) * 256 + k0 + c8 * 8];
        }
        #pragma unroll
        for (int i = 0; i < 4; ++i) {
            int f = tid + 256 * i;
            int row = f >> 3, c8 = f & 7;
            *(bf16x8*)&Bs[row * 72 + c8 * 8] =
                *(const bf16x8*)&W[(size_t)(n0 + row) * 256 + k0 + c8 * 8];
        }
        __syncthreads();
        #pragma unroll
        for (int ks = 0; ks < 64; ks += 32) {
            bf16x8 af[4], bfr[4];
            #pragma unroll
            for (int t = 0; t < 4; ++t) {
                af[t]  = *(const bf16x8*)&As[(wm + t * 16 + col) * 72 + ks + quad * 8];
                bfr[t] = *(const bf16x8*)&Bs[(wn + t * 16 + col) * 72 + ks + quad * 8];
            }
            #pragma unroll
            for (int mt = 0; mt < 4; ++mt)
                #pragma unroll
                for (int nt = 0; nt < 4; ++nt)
                    acc[mt][nt] = __builtin_amdgcn_mfma_f32_16x16x32_bf16(
                        af[mt], bfr[nt], acc[mt][nt], 0, 0, 0);
        }
    }

    // epilogue: m = m0+wm+mt*16+quad*4+r, n = n0+wn+nt*16+col
    #pragma unroll
    for (int mt = 0; mt < 4; ++mt) {
        const int mb = m0 + wm + mt * 16 + quad * 4;
        #pragma unroll
        for (int nt = 0; nt < 4; ++nt) {
            const int n = n0 + wn + nt * 16 + col;
            const float bn = bias[n];
            if (MODE == 1 && n >= 256) {
                // V: transposed, with sigma applied to token index (r in bits
                // 1:0 survives -> u16x4 store stays vectorized)
                const int nn = n - 256;
                const int b = mb >> 8, m1 = mb & 255;
                const int m1p = (m1 & 0xE3) | ((m1 & 0x0C) << 1) | ((m1 & 0x10) >> 2);
                u16x4 p;
                #pragma unroll
                for (int r = 0; r < 4; ++r)
                    p[r] = f2bf(acc[mt][nt][r] + bn);
                *(u16x4*)&outh1[(size_t)((b << 3) | (nn >> 5)) * 8192
                                + (nn & 31) * 256 + m1p] = p;
            } else {
                #pragma unroll
                for (int r = 0; r < 4; ++r) {
                    int m = mb + r;
                    int b = m >> 8, m1 = m & 255;
                    float v = acc[mt][nt][r] + bn;
                    if (MODE == 0) {
                        outh0[(size_t)((b << 3) | (n >> 5)) * 8192 + m1 * 32 + (n & 31)]
                            = f2bf(v * SCALE_Q);
                    } else if (MODE == 1) {
                        outh0[(size_t)((b << 3) | (n >> 5)) * 8192 + m1 * 32 + (n & 31)]
                            = f2bf(v);
                    } else {
                        outf[(size_t)m * 256 + n] = v;
                    }
                }
            }
        }
    }
}

// ---------------------------------------------------------------------------
// MFMA attention, swapped-operand QK^T (S^T = K @ Q^T): lane (col,quad) holds
// S[q=q0+col][j=jt*16+quad*4+r].  Softmax is lane-local + 2 shfl_xor.
// PV A-fragment packed directly from registers (k-dim permuted by sigma,
// matching vtb's layout) -> NO P LDS round-trip.  LDS 37376B.
// NOTE: plain launch_bounds(256) — a (256,4) min-waves hint capped the
// allocator at 64 VGPR and spilled acc[16] to scratch (598MB fetch, 250us).
// ---------------------------------------------------------------------------
__global__ __launch_bounds__(256)
void attn_mfma(const ushort* __restrict__ qh, const ushort* __restrict__ kb,
               const ushort* __restrict__ vt, const ushort* __restrict__ maskP,
               const ushort* __restrict__ biasP, ushort* __restrict__ xbuf)
{
    __shared__ ushort Ks[256 * 40];    // [j][d], stride 32+8
    __shared__ ushort Vts[32 * 264];   // [d][j'], stride 256+8

    // swizzle: g = w*16 + (b2*8 + h); window-sharing blocks adjacent
    const int g  = blockIdx.x;
    const int w  = g >> 4;
    const int b2 = (g >> 3) & 1, h = g & 7;
    const int b  = b2 * 128 + w;
    const int bh = b * 8 + h;

    const int tid  = threadIdx.x;
    const int lane = tid & 63, wave = tid >> 6;
    const int col  = lane & 15;
    const int quad = lane >> 4;

    const ushort* __restrict__ Qg = qh + (size_t)bh * 8192;
    const ushort* __restrict__ Kg = kb + (size_t)bh * 8192;
    const ushort* __restrict__ Vg = vt + (size_t)bh * 8192;
    const ushort* __restrict__ Mg = maskP + (size_t)w * 65536;
    const ushort* __restrict__ Bg = biasP + (size_t)h * 65536;

    for (int t = tid; t < 1024; t += 256) {
        int j = t >> 2, p = t & 3;
        *(bf16x8*)&Ks[j * 40 + p * 8] = *(const bf16x8*)&Kg[j * 32 + p * 8];
    }
    for (int t = tid; t < 1024; t += 256) {
        int d = t >> 5, p = t & 31;
        *(bf16x8*)&Vts[d * 264 + p * 8] = *(const bf16x8*)&Vg[d * 256 + p * 8];
    }
    __syncthreads();

    const f32x4 zero = {0.f, 0.f, 0.f, 0.f};

    for (int it = 0; it < 4; ++it) {
        const int q0   = (wave * 4 + it) * 16;
        const int qrow = q0 + col;

        // per-(q,quad) slice: 64 ushorts, local index l = jt*4 + r
        const ushort* mp  = &Mg[(size_t)qrow * 256 + quad * 64];
        const ushort* bp2 = &Bg[(size_t)qrow * 256 + quad * 64];

        // B operand: Q fragment (this wave's 16 q-rows)
        bf16x8 fq = *(const bf16x8*)&Qg[(size_t)qrow * 32 + quad * 8];

        // QK^T swapped: acc[jt][r] = S[q=qrow][j=jt*16+quad*4+r]
        f32x4 acc[16];
        #pragma unroll
        for (int jt = 0; jt < 16; ++jt) {
            bf16x8 fk = *(const bf16x8*)&Ks[(jt * 16 + col) * 40 + quad * 8];
            acc[jt] = __builtin_amdgcn_mfma_f32_16x16x32_bf16(fk, fq, zero, 0, 0, 0);
        }

        // mask + bias post-add (bf16), one uint4 pair (= 2 jt's) at a time
        // to keep peak register pressure low.  uint4 i2 covers l = i2*8..+8.
        #pragma unroll
        for (int i2 = 0; i2 < 8; ++i2) {
            uint4 mv4 = *(const uint4*)(mp  + i2 * 8);
            uint4 bv4 = *(const uint4*)(bp2 + i2 * 8);
            const int jt = i2 * 2;
            acc[jt][0]     += bflo(mv4.x) + bflo(bv4.x);
            acc[jt][1]     += bfhi(mv4.x) + bfhi(bv4.x);
            acc[jt][2]     += bflo(mv4.y) + bflo(bv4.y);
            acc[jt][3]     += bfhi(mv4.y) + bfhi(bv4.y);
            acc[jt + 1][0] += bflo(mv4.z) + bflo(bv4.z);
            acc[jt + 1][1] += bfhi(mv4.z) + bfhi(bv4.z);
            acc[jt + 1][2] += bflo(mv4.w) + bflo(bv4.w);
            acc[jt + 1][3] += bfhi(mv4.w) + bfhi(bv4.w);
        }

        // softmax over j for q=qrow: lane-local tree + cross-quad shfl
        float mv[16];
        #pragma unroll
        for (int jt = 0; jt < 16; ++jt)
            mv[jt] = fmaxf(fmaxf(acc[jt][0], acc[jt][1]),
                           fmaxf(acc[jt][2], acc[jt][3]));
        #pragma unroll
        for (int st = 8; st >= 1; st >>= 1)
            #pragma unroll
            for (int i = 0; i < 8; ++i)
                if (i < st) mv[i] = fmaxf(mv[i], mv[i + st]);
        float m = mv[0];
        m = fmaxf(m, __shfl_xor(m, 16));
        m = fmaxf(m, __shfl_xor(m, 32));

        float sv[16];
        #pragma unroll
        for (int jt = 0; jt < 16; ++jt) {
            #pragma unroll
            for (int r = 0; r < 4; ++r) {
                float e = __expf(acc[jt][r] - m);
                acc[jt][r] = e;
            }
            sv[jt] = (acc[jt][0] + acc[jt][1]) + (acc[jt][2] + acc[jt][3]);
        }
        #pragma unroll
        for (int st = 8; st >= 1; st >>= 1)
            #pragma unroll
            for (int i = 0; i < 8; ++i)
                if (i < st) sv[i] += sv[i + st];
        float s = sv[0];
        s += __shfl_xor(s, 16);
        s += __shfl_xor(s, 32);
        const float inv = 1.0f / s;

        // pack P (prescaled) straight from registers: k-slot (quad,t) of PV
        // call kc holds j = (2kc + t>>2)*16 + quad*4 + (t&3)  == sigma layout
        bf16x8 pa[8];
        #pragma unroll
        for (int kc = 0; kc < 8; ++kc)
            #pragma unroll
            for (int t2 = 0; t2 < 2; ++t2)
                #pragma unroll
                for (int r = 0; r < 4; ++r)
                    pa[kc][t2 * 4 + r] = (short)bfru(acc[kc * 2 + t2][r] * inv);

        // PV: x[q][d] accumulated over permuted j'
        f32x4 x0 = zero, x1 = zero;
        #pragma unroll
        for (int kc = 0; kc < 8; ++kc) {
            bf16x8 bv0 = *(const bf16x8*)&Vts[col * 264 + kc * 32 + quad * 8];
            bf16x8 bv1 = *(const bf16x8*)&Vts[(col + 16) * 264 + kc * 32 + quad * 8];
            x0 = __builtin_amdgcn_mfma_f32_16x16x32_bf16(pa[kc], bv0, x0, 0, 0, 0);
            x1 = __builtin_amdgcn_mfma_f32_16x16x32_bf16(pa[kc], bv1, x1, 0, 0, 0);
        }

        // out: lane holds O[q0+quad*4+r][d=col(+16)]
        #pragma unroll
        for (int r = 0; r < 4; ++r) {
            int row = q0 + quad * 4 + r;
            size_t base = (size_t)(b * 256 + row) * 256 + h * 32;
            xbuf[base + col]      = f2bf(x0[r]);
            xbuf[base + 16 + col] = f2bf(x1[r]);
        }
    }
}

// ---------------------------------------------------------------------------
extern "C" void kernel_launch(void* const* d_in, const int* in_sizes, int n_in,
                              void* d_out, int out_size, void* d_ws, size_t ws_size,
                              hipStream_t stream)
{
    const float* q          = (const float*)d_in[0];
    const float* kv         = (const float*)d_in[1];
    const float* mask       = (const float*)d_in[2];
    const float* Wq         = (const float*)d_in[3];
    const float* bq         = (const float*)d_in[4];
    const float* Wkv        = (const float*)d_in[5];
    const float* bkv        = (const float*)d_in[6];
    const float* bias_table = (const float*)d_in[7];
    const float* Wp         = (const float*)d_in[8];
    const float* bp         = (const float*)d_in[9];
    const int*   rel_index  = (const int*)d_in[10];
    float* out = (float*)d_out;

    // ws layout (with phase aliasing):
    //   0      qhb   32MB
    //  32M     qb16 (phase1) -> kbb (phase2)   32MB
    //  64M     vtb   32MB
    //  96M     kvb16 (phase1) -> xb (phase2)   32MB
    // 128M     maskP bf16 16MB
    // 144M     biasP bf16 1MB (2MB slot)
    // 146M     Wq/Wkv/Wp bf16
    char* ws = (char*)d_ws;
    ushort* qhb   = (ushort*)(ws);
    ushort* qb16  = (ushort*)(ws + (size_t)33554432);
    ushort* kbb   = (ushort*)(ws + (size_t)33554432);
    ushort* vtb   = (ushort*)(ws + (size_t)67108864);
    ushort* kvb16 = (ushort*)(ws + (size_t)100663296);
    ushort* xb    = (ushort*)(ws + (size_t)100663296);
    ushort* mP    = (ushort*)(ws + (size_t)134217728);
    ushort* bP    = (ushort*)(ws + (size_t)150994944);
    ushort* wqb   = (ushort*)(ws + (size_t)153092096);
    ushort* wkvb  = (ushort*)(ws + (size_t)153223168);
    ushort* wpb   = (ushort*)(ws + (size_t)153485312);

    dim3 blk(256);
    cvt_all<<<dim3(16512), blk, 0, stream>>>(q, kv, Wq, Wkv, Wp,
                                             qb16, kvb16, wqb, wkvb, wpb);
    mask_pre<<<dim3(8192), blk, 0, stream>>>(mask, mP);
    bias_pre<<<dim3(512),  blk, 0, stream>>>(bias_table, rel_index, bP);
    gemm_mfma<0><<<dim3(2, 512), blk, 0, stream>>>(qb16,  wqb,  bq,  nullptr, qhb, nullptr);
    gemm_mfma<1><<<dim3(4, 512), blk, 0, stream>>>(kvb16, wkvb, bkv, nullptr, kbb, vtb);
    attn_mfma<<<dim3(BH_TOTAL), blk, 0, stream>>>(qhb, kbb, vtb, mP, bP, xb);
    gemm_mfma<2><<<dim3(2, 512), blk, 0, stream>>>(xb, wpb, bp, out, nullptr, nullptr);
}

// Round 6
// 440.970 us; speedup vs baseline: 1.2519x; 1.0028x over previous
//
#include <hip/hip_runtime.h>

// Swin-3D window attention fwd. B_=256, nW=128, N1=N2=256, C=256, H=8, hd=32.
#define BH_TOTAL 2048
#define SCALE_Q 0.17677669529663687f

typedef unsigned short ushort;
typedef unsigned int uint;
typedef __attribute__((ext_vector_type(8))) short bf16x8;   // 8 bf16 = 4 VGPRs
typedef __attribute__((ext_vector_type(4))) ushort u16x4;
typedef __attribute__((ext_vector_type(4))) float f32x4;

static __device__ __forceinline__ ushort f2bf(float f) {      // RNE
    union { float f; uint u; } v; v.f = f;
    uint r = (v.u + 0x7fffu + ((v.u >> 16) & 1u)) >> 16;
    return (ushort)r;
}
static __device__ __forceinline__ ushort bfru(float f) {      // round-half-up (hot path)
    union { float f; uint u; } v; v.f = f;
    return (ushort)((v.u + 0x8000u) >> 16);
}
static __device__ __forceinline__ float bflo(uint w) {
    union { uint u; float f; } v; v.u = w << 16; return v.f;
}
static __device__ __forceinline__ float bfhi(uint w) {
    union { uint u; float f; } v; v.u = w & 0xffff0000u; return v.f;
}

// ---------------------------------------------------------------------------
// One-shot fp32 -> bf16 conversion of q, kv, Wq, Wkv, Wp.
// ---------------------------------------------------------------------------
__global__ __launch_bounds__(256)
void cvt_all(const float* __restrict__ q, const float* __restrict__ kv,
             const float* __restrict__ Wq, const float* __restrict__ Wkv,
             const float* __restrict__ Wp,
             ushort* __restrict__ qb, ushort* __restrict__ kvb,
             ushort* __restrict__ wqb, ushort* __restrict__ wkvb,
             ushort* __restrict__ wpb)
{
    const int bid = blockIdx.x, tid = threadIdx.x;
    const float* src; ushort* dst; int base;
    if (bid < 8192)       { src = q;   dst = qb;   base = bid; }
    else if (bid < 16384) { src = kv;  dst = kvb;  base = bid - 8192; }
    else if (bid < 16416) { src = Wq;  dst = wqb;  base = bid - 16384; }
    else if (bid < 16480) { src = Wkv; dst = wkvb; base = bid - 16416; }
    else                  { src = Wp;  dst = wpb;  base = bid - 16480; }
    size_t off = ((size_t)base * 256 + tid) * 8;
    float4 a = *(const float4*)&src[off];
    float4 b = *(const float4*)&src[off + 4];
    bf16x8 p = {(short)f2bf(a.x), (short)f2bf(a.y), (short)f2bf(a.z), (short)f2bf(a.w),
                (short)f2bf(b.x), (short)f2bf(b.y), (short)f2bf(b.z), (short)f2bf(b.w)};
    *(bf16x8*)&dst[off] = p;
}

// ---------------------------------------------------------------------------
// Swapped-QK lane layout: lane (col,quad) reg (jt,r) holds value at
// [q=col][j = jt*16 + quad*4 + r].  Flat per-lane index i = quad*64+jt*4+r.
// maskP[w][q][i] = mask[w][q][j(i)],  j(i) = ((i>>2)&15)*16 + (i>>6)*4 + (i&3)
// grid: (w, qb) = 128*64 blocks, 4 q-rows per block.
// ---------------------------------------------------------------------------
__global__ __launch_bounds__(256)
void mask_pre(const float* __restrict__ mask, ushort* __restrict__ maskP)
{
    __shared__ float rows[1024];
    const int w = blockIdx.x >> 6, qb = blockIdx.x & 63;
    const int tid = threadIdx.x;
    const float* src = mask + (size_t)w * 65536 + qb * 1024;
    #pragma unroll
    for (int i = 0; i < 4; ++i) rows[tid + 256 * i] = src[tid + 256 * i];
    __syncthreads();
    const int row = tid >> 6;          // 0..3
    const int ib  = (tid & 63) * 4;    // i base (4-aligned: r = i&3)
    u16x4 p;
    #pragma unroll
    for (int r = 0; r < 4; ++r) {
        int i = ib + r;
        int j = ((i >> 2) & 15) * 16 + (i >> 6) * 4 + (i & 3);
        p[r] = f2bf(rows[row * 256 + j]);
    }
    *(u16x4*)&maskP[(size_t)w * 65536 + (qb * 4 + row) * 256 + ib] = p;
}

// biasP[h][q][i] = bias_table[rel_index[q*256 + j(i)]*8 + h]  (bf16)
// grid: (h, qb) = 8*64 blocks
__global__ __launch_bounds__(256)
void bias_pre(const float* __restrict__ bias_table, const int* __restrict__ rel_index,
              ushort* __restrict__ biasP)
{
    __shared__ int idx[1024];
    const int h = blockIdx.x >> 6, qb = blockIdx.x & 63;
    const int tid = threadIdx.x;
    const int* src = rel_index + qb * 1024;
    #pragma unroll
    for (int i = 0; i < 4; ++i) idx[tid + 256 * i] = src[tid + 256 * i];
    __syncthreads();
    const int row = tid >> 6;
    const int ib  = (tid & 63) * 4;
    u16x4 p;
    #pragma unroll
    for (int r = 0; r < 4; ++r) {
        int i = ib + r;
        int j = ((i >> 2) & 15) * 16 + (i >> 6) * 4 + (i & 3);
        p[r] = f2bf(bias_table[idx[row * 256 + j] * 8 + h]);
    }
    *(u16x4*)&biasP[(size_t)h * 65536 + (qb * 4 + row) * 256 + ib] = p;
}

// ---------------------------------------------------------------------------
// bf16-MFMA GEMM: C(M x N) = A(M x 256) @ W(N x 256)^T + bias.
// Pre-converted bf16 A/W -> staging is pure b128 copies.
// MODE 1 V-half stores with k-permutation sigma (j' digit layout kc|quad|t2|r)
// so attn's PV can consume P directly from registers.
// ---------------------------------------------------------------------------
template<int MODE>
__global__ __launch_bounds__(256)
void gemm_mfma(const ushort* __restrict__ A, const ushort* __restrict__ W,
               const float* __restrict__ bias, float* __restrict__ outf,
               ushort* __restrict__ outh0, ushort* __restrict__ outh1)
{
    __shared__ ushort As[128 * 72];   // [m][k], stride 64+8
    __shared__ ushort Bs[128 * 72];   // [n][k]

    const int tid  = threadIdx.x;
    const int n0   = blockIdx.x * 128;
    const int m0   = blockIdx.y * 128;
    const int lane = tid & 63, wave = tid >> 6;
    const int col  = lane & 15, quad = lane >> 4;
    const int wm   = (wave >> 1) * 64, wn = (wave & 1) * 64;

    f32x4 acc[4][4];
    #pragma unroll
    for (int i = 0; i < 4; ++i)
        #pragma unroll
        for (int j = 0; j < 4; ++j)
            acc[i][j] = (f32x4){0.f, 0.f, 0.f, 0.f};

    for (int k0 = 0; k0 < 256; k0 += 64) {
        __syncthreads();
        #pragma unroll
        for (int i = 0; i < 4; ++i) {
            int f = tid + 256 * i;            // 1024 bf16x8 chunks
            int row = f >> 3, c8 = f & 7;
            *(bf16x8*)&As[row * 72 + c8 * 8] =
                *(const bf16x8*)&A[(size_t)(m0 + row) * 256 + k0 + c8 * 8];
        }
        #pragma unroll
        for (int i = 0; i < 4; ++i) {
            int f = tid + 256 * i;
            int row = f >> 3, c8 = f & 7;
            *(bf16x8*)&Bs[row * 72 + c8 * 8] =
                *(const bf16x8*)&W[(size_t)(n0 + row) * 256 + k0 + c8 * 8];
        }
        __syncthreads();
        #pragma unroll
        for (int ks = 0; ks < 64; ks += 32) {
            bf16x8 af[4], bfr[4];
            #pragma unroll
            for (int t = 0; t < 4; ++t) {
                af[t]  = *(const bf16x8*)&As[(wm + t * 16 + col) * 72 + ks + quad * 8];
                bfr[t] = *(const bf16x8*)&Bs[(wn + t * 16 + col) * 72 + ks + quad * 8];
            }
            #pragma unroll
            for (int mt = 0; mt < 4; ++mt)
                #pragma unroll
                for (int nt = 0; nt < 4; ++nt)
                    acc[mt][nt] = __builtin_amdgcn_mfma_f32_16x16x32_bf16(
                        af[mt], bfr[nt], acc[mt][nt], 0, 0, 0);
        }
    }

    // epilogue: m = m0+wm+mt*16+quad*4+r, n = n0+wn+nt*16+col
    #pragma unroll
    for (int mt = 0; mt < 4; ++mt) {
        const int mb = m0 + wm + mt * 16 + quad * 4;
        #pragma unroll
        for (int nt = 0; nt < 4; ++nt) {
            const int n = n0 + wn + nt * 16 + col;
            const float bn = bias[n];
            if (MODE == 1 && n >= 256) {
                // V: transposed, with sigma applied to token index (r in bits
                // 1:0 survives -> u16x4 store stays vectorized)
                const int nn = n - 256;
                const int b = mb >> 8, m1 = mb & 255;
                const int m1p = (m1 & 0xE3) | ((m1 & 0x0C) << 1) | ((m1 & 0x10) >> 2);
                u16x4 p;
                #pragma unroll
                for (int r = 0; r < 4; ++r)
                    p[r] = f2bf(acc[mt][nt][r] + bn);
                *(u16x4*)&outh1[(size_t)((b << 3) | (nn >> 5)) * 8192
                                + (nn & 31) * 256 + m1p] = p;
            } else {
                #pragma unroll
                for (int r = 0; r < 4; ++r) {
                    int m = mb + r;
                    int b = m >> 8, m1 = m & 255;
                    float v = acc[mt][nt][r] + bn;
                    if (MODE == 0) {
                        outh0[(size_t)((b << 3) | (n >> 5)) * 8192 + m1 * 32 + (n & 31)]
                            = f2bf(v * SCALE_Q);
                    } else if (MODE == 1) {
                        outh0[(size_t)((b << 3) | (n >> 5)) * 8192 + m1 * 32 + (n & 31)]
                            = f2bf(v);
                    } else {
                        outf[(size_t)m * 256 + n] = v;
                    }
                }
            }
        }
    }
}

// ---------------------------------------------------------------------------
// MFMA attention, swapped-operand QK^T (S^T = K @ Q^T): lane (col,quad) holds
// S[q=q0+col][j=jt*16+quad*4+r].  Softmax is lane-local + 2 shfl_xor.
// PV A-fragment packed from the QK accumulator per-kc (transient, no pa[]
// array); softmax reductions are linear scalars (no mv[]/sv[] arrays).
// Target: VGPR <= 128 (the occupancy cliff: waves/CU halve above 128).
// LDS 37376B -> 4 blocks/CU.  NO min-waves launch_bounds hint (r3 spill).
// ---------------------------------------------------------------------------
__global__ __launch_bounds__(256)
void attn_mfma(const ushort* __restrict__ qh, const ushort* __restrict__ kb,
               const ushort* __restrict__ vt, const ushort* __restrict__ maskP,
               const ushort* __restrict__ biasP, ushort* __restrict__ xbuf)
{
    __shared__ ushort Ks[256 * 40];    // [j][d], stride 32+8
    __shared__ ushort Vts[32 * 264];   // [d][j'], stride 256+8

    // swizzle: g = w*16 + (b2*8 + h); window-sharing blocks adjacent
    const int g  = blockIdx.x;
    const int w  = g >> 4;
    const int b2 = (g >> 3) & 1, h = g & 7;
    const int b  = b2 * 128 + w;
    const int bh = b * 8 + h;

    const int tid  = threadIdx.x;
    const int lane = tid & 63, wave = tid >> 6;
    const int col  = lane & 15;
    const int quad = lane >> 4;

    const ushort* __restrict__ Qg = qh + (size_t)bh * 8192;
    const ushort* __restrict__ Kg = kb + (size_t)bh * 8192;
    const ushort* __restrict__ Vg = vt + (size_t)bh * 8192;
    const ushort* __restrict__ Mg = maskP + (size_t)w * 65536;
    const ushort* __restrict__ Bg = biasP + (size_t)h * 65536;

    for (int t = tid; t < 1024; t += 256) {
        int j = t >> 2, p = t & 3;
        *(bf16x8*)&Ks[j * 40 + p * 8] = *(const bf16x8*)&Kg[j * 32 + p * 8];
    }
    for (int t = tid; t < 1024; t += 256) {
        int d = t >> 5, p = t & 31;
        *(bf16x8*)&Vts[d * 264 + p * 8] = *(const bf16x8*)&Vg[d * 256 + p * 8];
    }
    __syncthreads();

    const f32x4 zero = {0.f, 0.f, 0.f, 0.f};

    for (int it = 0; it < 4; ++it) {
        const int q0   = (wave * 4 + it) * 16;
        const int qrow = q0 + col;

        // per-(q,quad) slice: 64 ushorts, local index l = jt*4 + r
        const ushort* mp  = &Mg[(size_t)qrow * 256 + quad * 64];
        const ushort* bp2 = &Bg[(size_t)qrow * 256 + quad * 64];

        // B operand: Q fragment (this wave's 16 q-rows)
        bf16x8 fq = *(const bf16x8*)&Qg[(size_t)qrow * 32 + quad * 8];

        // QK^T swapped: acc[jt][r] = S[q=qrow][j=jt*16+quad*4+r]
        f32x4 acc[16];
        #pragma unroll
        for (int jt = 0; jt < 16; ++jt) {
            bf16x8 fk = *(const bf16x8*)&Ks[(jt * 16 + col) * 40 + quad * 8];
            acc[jt] = __builtin_amdgcn_mfma_f32_16x16x32_bf16(fk, fq, zero, 0, 0, 0);
        }

        // mask + bias post-add (bf16), one uint4 pair (= 2 jt's) at a time
        #pragma unroll
        for (int i2 = 0; i2 < 8; ++i2) {
            uint4 mv4 = *(const uint4*)(mp  + i2 * 8);
            uint4 bv4 = *(const uint4*)(bp2 + i2 * 8);
            const int jt = i2 * 2;
            acc[jt][0]     += bflo(mv4.x) + bflo(bv4.x);
            acc[jt][1]     += bfhi(mv4.x) + bfhi(bv4.x);
            acc[jt][2]     += bflo(mv4.y) + bflo(bv4.y);
            acc[jt][3]     += bfhi(mv4.y) + bfhi(bv4.y);
            acc[jt + 1][0] += bflo(mv4.z) + bflo(bv4.z);
            acc[jt + 1][1] += bfhi(mv4.z) + bfhi(bv4.z);
            acc[jt + 1][2] += bflo(mv4.w) + bflo(bv4.w);
            acc[jt + 1][3] += bfhi(mv4.w) + bfhi(bv4.w);
        }

        // softmax over j for q=qrow: linear lane-local reduce + cross-quad shfl
        float m = fmaxf(fmaxf(acc[0][0], acc[0][1]), fmaxf(acc[0][2], acc[0][3]));
        #pragma unroll
        for (int jt = 1; jt < 16; ++jt)
            m = fmaxf(m, fmaxf(fmaxf(acc[jt][0], acc[jt][1]),
                               fmaxf(acc[jt][2], acc[jt][3])));
        m = fmaxf(m, __shfl_xor(m, 16));
        m = fmaxf(m, __shfl_xor(m, 32));

        float s = 0.f;
        #pragma unroll
        for (int jt = 0; jt < 16; ++jt) {
            acc[jt][0] = __expf(acc[jt][0] - m);
            acc[jt][1] = __expf(acc[jt][1] - m);
            acc[jt][2] = __expf(acc[jt][2] - m);
            acc[jt][3] = __expf(acc[jt][3] - m);
            s += (acc[jt][0] + acc[jt][1]) + (acc[jt][2] + acc[jt][3]);
        }
        s += __shfl_xor(s, 16);
        s += __shfl_xor(s, 32);
        const float inv = 1.0f / s;

        // PV with pack interleaved per kc (transient pa fragment).
        // k-slot (quad,t) of call kc holds j = (2kc + t>>2)*16 + quad*4 + (t&3)
        // == sigma layout baked into vtb.
        f32x4 x0 = zero, x1 = zero;
        #pragma unroll
        for (int kc = 0; kc < 8; ++kc) {
            bf16x8 pa;
            #pragma unroll
            for (int t2 = 0; t2 < 2; ++t2)
                #pragma unroll
                for (int r = 0; r < 4; ++r)
                    pa[t2 * 4 + r] = (short)bfru(acc[kc * 2 + t2][r] * inv);
            bf16x8 bv0 = *(const bf16x8*)&Vts[col * 264 + kc * 32 + quad * 8];
            bf16x8 bv1 = *(const bf16x8*)&Vts[(col + 16) * 264 + kc * 32 + quad * 8];
            x0 = __builtin_amdgcn_mfma_f32_16x16x32_bf16(pa, bv0, x0, 0, 0, 0);
            x1 = __builtin_amdgcn_mfma_f32_16x16x32_bf16(pa, bv1, x1, 0, 0, 0);
        }

        // out: lane holds O[q0+quad*4+r][d=col(+16)]
        #pragma unroll
        for (int r = 0; r < 4; ++r) {
            int row = q0 + quad * 4 + r;
            size_t base = (size_t)(b * 256 + row) * 256 + h * 32;
            xbuf[base + col]      = f2bf(x0[r]);
            xbuf[base + 16 + col] = f2bf(x1[r]);
        }
    }
}

// ---------------------------------------------------------------------------
extern "C" void kernel_launch(void* const* d_in, const int* in_sizes, int n_in,
                              void* d_out, int out_size, void* d_ws, size_t ws_size,
                              hipStream_t stream)
{
    const float* q          = (const float*)d_in[0];
    const float* kv         = (const float*)d_in[1];
    const float* mask       = (const float*)d_in[2];
    const float* Wq         = (const float*)d_in[3];
    const float* bq         = (const float*)d_in[4];
    const float* Wkv        = (const float*)d_in[5];
    const float* bkv        = (const float*)d_in[6];
    const float* bias_table = (const float*)d_in[7];
    const float* Wp         = (const float*)d_in[8];
    const float* bp         = (const float*)d_in[9];
    const int*   rel_index  = (const int*)d_in[10];
    float* out = (float*)d_out;

    // ws layout (with phase aliasing):
    //   0      qhb   32MB
    //  32M     qb16 (phase1) -> kbb (phase2)   32MB
    //  64M     vtb   32MB
    //  96M     kvb16 (phase1) -> xb (phase2)   32MB
    // 128M     maskP bf16 16MB
    // 144M     biasP bf16 1MB (2MB slot)
    // 146M     Wq/Wkv/Wp bf16
    char* ws = (char*)d_ws;
    ushort* qhb   = (ushort*)(ws);
    ushort* qb16  = (ushort*)(ws + (size_t)33554432);
    ushort* kbb   = (ushort*)(ws + (size_t)33554432);
    ushort* vtb   = (ushort*)(ws + (size_t)67108864);
    ushort* kvb16 = (ushort*)(ws + (size_t)100663296);
    ushort* xb    = (ushort*)(ws + (size_t)100663296);
    ushort* mP    = (ushort*)(ws + (size_t)134217728);
    ushort* bP    = (ushort*)(ws + (size_t)150994944);
    ushort* wqb   = (ushort*)(ws + (size_t)153092096);
    ushort* wkvb  = (ushort*)(ws + (size_t)153223168);
    ushort* wpb   = (ushort*)(ws + (size_t)153485312);

    dim3 blk(256);
    cvt_all<<<dim3(16512), blk, 0, stream>>>(q, kv, Wq, Wkv, Wp,
                                             qb16, kvb16, wqb, wkvb, wpb);
    mask_pre<<<dim3(8192), blk, 0, stream>>>(mask, mP);
    bias_pre<<<dim3(512),  blk, 0, stream>>>(bias_table, rel_index, bP);
    gemm_mfma<0><<<dim3(2, 512), blk, 0, stream>>>(qb16,  wqb,  bq,  nullptr, qhb, nullptr);
    gemm_mfma<1><<<dim3(4, 512), blk, 0, stream>>>(kvb16, wkvb, bkv, nullptr, kbb, vtb);
    attn_mfma<<<dim3(BH_TOTAL), blk, 0, stream>>>(qhb, kbb, vtb, mP, bP, xb);
    gemm_mfma<2><<<dim3(2, 512), blk, 0, stream>>>(xb, wpb, bp, out, nullptr, nullptr);
}